// Round 6
// baseline (285.030 us; speedup 1.0000x reference)
//
#include <hip/hip_runtime.h>
#include <math.h>

#define D_MODEL 1024
#define D_STATE 128
#define SEQ_LEN 4096
#define BATCH 4
#define NTOK (BATCH * SEQ_LEN)      // 16384
#define LN_EPS 1e-3f
#define NCHUNK 128
#define LCHUNK (SEQ_LEN / NCHUNK)   // 32

typedef __attribute__((ext_vector_type(8))) short bf16x8;
typedef __attribute__((ext_vector_type(4))) float f32x4;

__device__ __forceinline__ short f2bf(float f) {
    union { float f; unsigned u; } v; v.f = f;
    unsigned r = v.u + 0x7FFFu + ((v.u >> 16) & 1u);   // RNE
    return (short)(r >> 16);
}
__device__ __forceinline__ float bf2f(short s) {
    union { unsigned u; float f; } v; v.u = ((unsigned)(unsigned short)s) << 16;
    return v.f;
}

// ------- fused weight prep + LayerNorm in ONE launch (independent blocks) ---
// blocks 0..2559: weight transposes; 2560: bias3; 2561..18944: LN rows.
__global__ __launch_bounds__(256) void prep_ln_kernel(
    const float* __restrict__ W_in, const float* __restrict__ W_xs,
    const float* __restrict__ W_B, const float* __restrict__ W_C,
    const float* __restrict__ W_so, const float* __restrict__ W_out,
    const float* __restrict__ bB, const float* __restrict__ bC,
    short* __restrict__ W_inT, short* __restrict__ W3T,
    short* __restrict__ W_soT, short* __restrict__ W_outT,
    float* __restrict__ bias3,
    const float* __restrict__ x, const float* __restrict__ gamma,
    const float* __restrict__ beta, short* __restrict__ xn_bf) {
    int blk = blockIdx.x;
    if (blk >= 2561) {
        // ---- LayerNorm row -> bf16 ----
        int row = blk - 2561;
        int t = threadIdx.y * 32 + threadIdx.x;    // 0..255
        const float4* xr = (const float4*)(x + (size_t)row * D_MODEL);
        float4 v = xr[t];
        float s1 = v.x + v.y + v.z + v.w;
        float s2 = v.x * v.x + v.y * v.y + v.z * v.z + v.w * v.w;
        for (int off = 32; off; off >>= 1) {
            s1 += __shfl_down(s1, off);
            s2 += __shfl_down(s2, off);
        }
        __shared__ float ls1[4], ls2[4];
        int wid = t >> 6, lane = t & 63;
        if (lane == 0) { ls1[wid] = s1; ls2[wid] = s2; }
        __syncthreads();
        s1 = ls1[0] + ls1[1] + ls1[2] + ls1[3];
        s2 = ls2[0] + ls2[1] + ls2[2] + ls2[3];
        float mu = s1 * (1.0f / D_MODEL);
        float var = s2 * (1.0f / D_MODEL) - mu * mu;
        float r = rsqrtf(var + LN_EPS);
        float4 g = ((const float4*)gamma)[t];
        float4 b = ((const float4*)beta)[t];
        short4 o;
        o.x = f2bf((v.x - mu) * r * g.x + b.x);
        o.y = f2bf((v.y - mu) * r * g.y + b.y);
        o.z = f2bf((v.z - mu) * r * g.z + b.z);
        o.w = f2bf((v.w - mu) * r * g.w + b.w);
        ((short4*)(xn_bf + (size_t)row * D_MODEL))[t] = o;
        return;
    }
    const float* in; short* out; int K, N, tile;
    if (blk < 1024)      { in = W_in;  out = W_inT;           K = 1024; N = 1024; tile = blk; }
    else if (blk < 1152) { in = W_xs;  out = W3T;             K = 1024; N = 128;  tile = blk - 1024; }
    else if (blk < 1280) { in = W_B;   out = W3T + 128*1024;  K = 1024; N = 128;  tile = blk - 1152; }
    else if (blk < 1408) { in = W_C;   out = W3T + 256*1024;  K = 1024; N = 128;  tile = blk - 1280; }
    else if (blk < 1536) { in = W_so;  out = W_soT;           K = 128;  N = 1024; tile = blk - 1408; }
    else if (blk < 2560) { in = W_out; out = W_outT;          K = 1024; N = 1024; tile = blk - 1536; }
    else {
        int t = threadIdx.y * 32 + threadIdx.x;
        for (int n = t; n < 384; n += 256)
            bias3[n] = (n < 128) ? 0.f : ((n < 256) ? bB[n - 128] : bC[n - 256]);
        return;
    }
    __shared__ float t32[32][33];
    int ntiles = N / 32;
    int nb = (tile % ntiles) * 32, kb = (tile / ntiles) * 32;
    int tx = threadIdx.x, ty = threadIdx.y;   // 32 x 8
#pragma unroll
    for (int i = 0; i < 4; ++i)
        t32[ty + 8 * i][tx] = in[(size_t)(kb + ty + 8 * i) * N + nb + tx];
    __syncthreads();
#pragma unroll
    for (int i = 0; i < 4; ++i)
        out[(size_t)(nb + ty + 8 * i) * K + kb + tx] = f2bf(t32[tx][ty + 8 * i]);
}

// ---------------- bf16 MFMA GEMM: BK=64, XOR-swizzled LDS, XCD swizzle ------
// C[M,N] = A[M,K](bf16) @ BT[N,K](bf16)^T, fp32 accum. 1-D grid of Mt*Nt tiles.
// LDS layout: row-major [row][8 slots of 8 bf16], slot = kc8 ^ (row&7) so the
// fragment ds_read_b128s of 16 consecutive-row lanes spread over all 32 banks.
template<int HAS_BIAS, int HAS_ADD, int ADD_BF, int HAS_SCALE, int OUT_F32, int OUT_BF, int SWZ>
__global__ __launch_bounds__(256, 4) void gemm_bf16(
    const short* __restrict__ A, const short* __restrict__ BT,
    const float* __restrict__ bias,
    const float* __restrict__ addf, const short* __restrict__ addb,
    const float* __restrict__ addscale,
    float* __restrict__ Cf, short* __restrict__ Cbf,
    int Mt, int Nt, int K) {
    __shared__ short As[128 * 64];   // 16 KiB
    __shared__ short Bs[128 * 64];   // 16 KiB
    int p = blockIdx.x;
    int mtile, ntile;
    if (SWZ) {           // xcd = p&7; each XCD runs (m, n=0..7) consecutively
        int k = p & 7, q = p >> 3;
        ntile = q & 7;
        mtile = k + 8 * (q >> 3);
    } else {
        mtile = p % Mt;
        ntile = p / Mt;
    }
    int m0 = mtile * 128, n0 = ntile * 128;
    int N = Nt * 128;
    int tid = threadIdx.x;
    int lane = tid & 63;
    int w = tid >> 6;
    int quad = lane >> 4, r16 = lane & 15;
    int wm = (w & 1) * 64, wn = (w >> 1) * 64;

    f32x4 acc[4][4] = {};

    for (int k0 = 0; k0 < K; k0 += 64) {
#pragma unroll
        for (int it = 0; it < 4; ++it) {
            int seg = it * 256 + tid;          // 0..1023
            int row = seg >> 3, slot = seg & 7;
            int kc8 = slot ^ (row & 7);
            const short* gp = A + (size_t)(m0 + row) * K + k0 + kc8 * 8;
            __builtin_amdgcn_global_load_lds(
                (const __attribute__((address_space(1))) unsigned*)gp,
                (__attribute__((address_space(3))) unsigned*)(As + seg * 8), 16, 0, 0);
        }
#pragma unroll
        for (int it = 0; it < 4; ++it) {
            int seg = it * 256 + tid;
            int row = seg >> 3, slot = seg & 7;
            int kc8 = slot ^ (row & 7);
            const short* gp = BT + (size_t)(n0 + row) * K + k0 + kc8 * 8;
            __builtin_amdgcn_global_load_lds(
                (const __attribute__((address_space(1))) unsigned*)gp,
                (__attribute__((address_space(3))) unsigned*)(Bs + seg * 8), 16, 0, 0);
        }
        __syncthreads();

        const short* abase = As + (wm + r16) * 64;
        const short* bbase = Bs + (wn + r16) * 64;
        int sw = r16 & 7;
#pragma unroll
        for (int kk = 0; kk < 2; ++kk) {
            int phys = ((quad + 4 * kk) ^ sw) * 8;
            bf16x8 af[4], bfr[4];
#pragma unroll
            for (int i = 0; i < 4; ++i) af[i] = *(const bf16x8*)(abase + i * 16 * 64 + phys);
#pragma unroll
            for (int j = 0; j < 4; ++j) bfr[j] = *(const bf16x8*)(bbase + j * 16 * 64 + phys);
#pragma unroll
            for (int i = 0; i < 4; ++i)
#pragma unroll
                for (int j = 0; j < 4; ++j)
                    acc[i][j] = __builtin_amdgcn_mfma_f32_16x16x32_bf16(af[i], bfr[j], acc[i][j], 0, 0, 0);
        }
        __syncthreads();
    }

#pragma unroll
    for (int i = 0; i < 4; ++i) {
#pragma unroll
        for (int j = 0; j < 4; ++j) {
            int col = n0 + wn + j * 16 + r16;
            float bv = HAS_BIAS ? bias[col] : 0.f;
            float sc = HAS_SCALE ? addscale[col] : 1.f;
#pragma unroll
            for (int pr = 0; pr < 4; ++pr) {
                int row = m0 + wm + i * 16 + quad * 4 + pr;
                float v = acc[i][j][pr] + bv;
                if (HAS_ADD) {
                    float av = ADD_BF ? bf2f(addb[(size_t)row * N + col])
                                      : addf[(size_t)row * N + col];
                    v += sc * av;
                }
                if (OUT_F32) Cf[(size_t)row * N + col] = v;
                if (OUT_BF) Cbf[(size_t)row * N + col] = f2bf(v);
            }
        }
    }
}

// ---------------- Chunked linear scan (exact FFT-conv replacement) ----------
// p1: per-chunk end-state only (no hbuf).  p3: recompute local scan + per-block
// carry from Ebuf (absorbs old p2), fused *C_sel -> ys_bf.
__global__ __launch_bounds__(128) void scan_p1(const float* __restrict__ s3,
                                               const float* __restrict__ A_log,
                                               float* __restrict__ Ebuf) {
    int s = threadIdx.x;
    int c = blockIdx.x, b = blockIdx.y;
    float a = expf(-expf(A_log[s]));
    float h = 0.f;
    size_t base = (size_t)b * SEQ_LEN + (size_t)c * LCHUNK;
#pragma unroll 8
    for (int i = 0; i < LCHUNK; ++i) {
        size_t r = base + i;
        float u = s3[r * 384 + s] * s3[r * 384 + 128 + s];
        h = a * h + u;
    }
    Ebuf[((size_t)b * NCHUNK + c) * 128 + s] = h;
}

__global__ __launch_bounds__(128) void scan_p3(const float* __restrict__ s3,
                                               const float* __restrict__ A_log,
                                               const float* __restrict__ Ebuf,
                                               short* __restrict__ ys_bf) {
    int s = threadIdx.x;
    int c = blockIdx.x, b = blockIdx.y;
    float al = -expf(A_log[s]);
    float a = expf(al);
    float pw = expf(al * (float)LCHUNK);
    // carry = decayed scan over prior chunk end-states (same op order as old p2)
    float G = 0.f;
    const float* Eb = Ebuf + (size_t)b * NCHUNK * 128 + s;
    int c0 = 0;
    for (; c0 + 16 <= c; c0 += 16) {
        float e[16];
#pragma unroll
        for (int t = 0; t < 16; ++t) e[t] = Eb[(size_t)(c0 + t) * 128];
#pragma unroll
        for (int t = 0; t < 16; ++t) G = pw * G + e[t];
    }
    for (; c0 < c; ++c0) G = pw * G + Eb[(size_t)c0 * 128];
    float carry = G;

    float h = 0.f, p = a;
    size_t base = (size_t)b * SEQ_LEN + (size_t)c * LCHUNK;
#pragma unroll 8
    for (int i = 0; i < LCHUNK; ++i) {
        size_t r = base + i;
        float u = s3[r * 384 + s] * s3[r * 384 + 128 + s];
        h = a * h + u;                      // bitwise == old hbuf value
        float hv = h + p * carry;
        p *= a;
        ys_bf[r * 128 + s] = f2bf(hv * s3[r * 384 + 256 + s]);
    }
}

extern "C" void kernel_launch(void* const* d_in, const int* in_sizes, int n_in,
                              void* d_out, int out_size, void* d_ws, size_t ws_size,
                              hipStream_t stream) {
    const float* x     = (const float*)d_in[0];
    const float* ln_g  = (const float*)d_in[1];
    const float* ln_b  = (const float*)d_in[2];
    const float* W_in  = (const float*)d_in[3];
    const float* b_in  = (const float*)d_in[4];
    const float* W_xs  = (const float*)d_in[5];
    const float* W_B   = (const float*)d_in[6];
    const float* b_B   = (const float*)d_in[7];
    const float* W_C   = (const float*)d_in[8];
    const float* b_C   = (const float*)d_in[9];
    const float* A_log = (const float*)d_in[10];
    const float* Dvec  = (const float*)d_in[11];
    const float* W_so  = (const float*)d_in[12];
    const float* W_out = (const float*)d_in[13];
    const float* b_out = (const float*)d_in[14];
    float* out = (float*)d_out;

    // ---- workspace carve (bytes) ----
    char* w = (char*)d_ws;
    size_t off = 0;
    short* xn_bf = (short*)(w + off);                       // region 0: 32 MiB
    short* ys_bf = (short*)(w + off + 8388608);             //   reuses region 0 after GEMM1
    off += (size_t)NTOK * D_MODEL * 2;
    short* z_bf  = (short*)(w + off);                       // region 1: 32 MiB
    off += (size_t)NTOK * D_MODEL * 2;
    short* y1_bf = (short*)(w + off);                       // region 2: 32 MiB
    off += (size_t)NTOK * D_MODEL * 2;
    float* s3    = (float*)(w + off); off += (size_t)NTOK * 384 * 4;       // 24 MiB
    float* Ebuf  = (float*)(w + off); off += (size_t)BATCH * NCHUNK * 128 * 4;
    short* W_inT  = (short*)(w + off); off += (size_t)D_MODEL * D_MODEL * 2;
    short* W3T    = (short*)(w + off); off += (size_t)384 * D_MODEL * 2;
    short* W_soT  = (short*)(w + off); off += (size_t)D_MODEL * D_STATE * 2;
    short* W_outT = (short*)(w + off); off += (size_t)D_MODEL * D_MODEL * 2;
    float* bias3  = (float*)(w + off); off += 2048;

    // ---- weight prep + LayerNorm (single launch; independent blocks) ----
    prep_ln_kernel<<<2561 + NTOK, dim3(32, 8), 0, stream>>>(
        W_in, W_xs, W_B, W_C, W_so, W_out, b_B, b_C,
        W_inT, W3T, W_soT, W_outT, bias3,
        x, ln_g, ln_b, xn_bf);

    const int Mt = NTOK / 128;   // 128
    // ---- 2) z = xn @ W_in + b_in  (bf16) ----
    gemm_bf16<1, 0, 0, 0, 0, 1, 1><<<Mt * 8, 256, 0, stream>>>(
        xn_bf, W_inT, b_in, nullptr, nullptr, nullptr,
        nullptr, z_bf, Mt, 8, D_MODEL);

    // ---- 3) s3 = z @ [W_xs|W_B|W_C] + bias3  (f32) ----
    gemm_bf16<1, 0, 0, 0, 1, 0, 0><<<Mt * 3, 256, 0, stream>>>(
        z_bf, W3T, bias3, nullptr, nullptr, nullptr,
        s3, nullptr, Mt, 3, D_MODEL);

    // ---- 4) chunked scan (fp32 exact), fused *C_sel -> ys_bf ----
    scan_p1<<<dim3(NCHUNK, BATCH), 128, 0, stream>>>(s3, A_log, Ebuf);
    scan_p3<<<dim3(NCHUNK, BATCH), 128, 0, stream>>>(s3, A_log, Ebuf, ys_bf);

    // ---- 5) y1 = ys @ W_so + D*z  (bf16 out, bf16 addmat) ----
    gemm_bf16<0, 1, 1, 1, 0, 1, 1><<<Mt * 8, 256, 0, stream>>>(
        ys_bf, W_soT, nullptr, nullptr, z_bf, Dvec,
        nullptr, y1_bf, Mt, 8, D_STATE);

    // ---- 6) out = y1 @ W_out + b_out + x (f32 residual) ----
    gemm_bf16<1, 1, 0, 0, 1, 0, 1><<<Mt * 8, 256, 0, stream>>>(
        y1_bf, W_outT, b_out, x, nullptr, nullptr,
        out, nullptr, Mt, 8, D_MODEL);
}

// Round 8
// 276.923 us; speedup vs baseline: 1.0293x; 1.0293x over previous
//
#include <hip/hip_runtime.h>
#include <math.h>

#define D_MODEL 1024
#define D_STATE 128
#define SEQ_LEN 4096
#define BATCH 4
#define NTOK (BATCH * SEQ_LEN)      // 16384
#define LN_EPS 1e-3f
#define NCHUNK 128
#define LCHUNK (SEQ_LEN / NCHUNK)   // 32

typedef __attribute__((ext_vector_type(8))) short bf16x8;
typedef __attribute__((ext_vector_type(4))) float f32x4;

__device__ __forceinline__ short f2bf(float f) {
    union { float f; unsigned u; } v; v.f = f;
    unsigned r = v.u + 0x7FFFu + ((v.u >> 16) & 1u);   // RNE
    return (short)(r >> 16);
}
__device__ __forceinline__ float bf2f(short s) {
    union { unsigned u; float f; } v; v.u = ((unsigned)(unsigned short)s) << 16;
    return v.f;
}

// ------- fused weight prep + LayerNorm in ONE launch (independent blocks) ---
// blocks 0..2559: weight transposes; 2560: bias3; 2561..18944: LN rows.
__global__ __launch_bounds__(256) void prep_ln_kernel(
    const float* __restrict__ W_in, const float* __restrict__ W_xs,
    const float* __restrict__ W_B, const float* __restrict__ W_C,
    const float* __restrict__ W_so, const float* __restrict__ W_out,
    const float* __restrict__ bB, const float* __restrict__ bC,
    short* __restrict__ W_inT, short* __restrict__ W3T,
    short* __restrict__ W_soT, short* __restrict__ W_outT,
    float* __restrict__ bias3,
    const float* __restrict__ x, const float* __restrict__ gamma,
    const float* __restrict__ beta, short* __restrict__ xn_bf) {
    int blk = blockIdx.x;
    if (blk >= 2561) {
        // ---- LayerNorm row -> bf16 ----
        int row = blk - 2561;
        int t = threadIdx.y * 32 + threadIdx.x;    // 0..255
        const float4* xr = (const float4*)(x + (size_t)row * D_MODEL);
        float4 v = xr[t];
        float s1 = v.x + v.y + v.z + v.w;
        float s2 = v.x * v.x + v.y * v.y + v.z * v.z + v.w * v.w;
        for (int off = 32; off; off >>= 1) {
            s1 += __shfl_down(s1, off);
            s2 += __shfl_down(s2, off);
        }
        __shared__ float ls1[4], ls2[4];
        int wid = t >> 6, lane = t & 63;
        if (lane == 0) { ls1[wid] = s1; ls2[wid] = s2; }
        __syncthreads();
        s1 = ls1[0] + ls1[1] + ls1[2] + ls1[3];
        s2 = ls2[0] + ls2[1] + ls2[2] + ls2[3];
        float mu = s1 * (1.0f / D_MODEL);
        float var = s2 * (1.0f / D_MODEL) - mu * mu;
        float r = rsqrtf(var + LN_EPS);
        float4 g = ((const float4*)gamma)[t];
        float4 b = ((const float4*)beta)[t];
        short4 o;
        o.x = f2bf((v.x - mu) * r * g.x + b.x);
        o.y = f2bf((v.y - mu) * r * g.y + b.y);
        o.z = f2bf((v.z - mu) * r * g.z + b.z);
        o.w = f2bf((v.w - mu) * r * g.w + b.w);
        ((short4*)(xn_bf + (size_t)row * D_MODEL))[t] = o;
        return;
    }
    const float* in; short* out; int K, N, tile;
    if (blk < 1024)      { in = W_in;  out = W_inT;           K = 1024; N = 1024; tile = blk; }
    else if (blk < 1152) { in = W_xs;  out = W3T;             K = 1024; N = 128;  tile = blk - 1024; }
    else if (blk < 1280) { in = W_B;   out = W3T + 128*1024;  K = 1024; N = 128;  tile = blk - 1152; }
    else if (blk < 1408) { in = W_C;   out = W3T + 256*1024;  K = 1024; N = 128;  tile = blk - 1280; }
    else if (blk < 1536) { in = W_so;  out = W_soT;           K = 128;  N = 1024; tile = blk - 1408; }
    else if (blk < 2560) { in = W_out; out = W_outT;          K = 1024; N = 1024; tile = blk - 1536; }
    else {
        int t = threadIdx.y * 32 + threadIdx.x;
        for (int n = t; n < 384; n += 256)
            bias3[n] = (n < 128) ? 0.f : ((n < 256) ? bB[n - 128] : bC[n - 256]);
        return;
    }
    __shared__ float t32[32][33];
    int ntiles = N / 32;
    int nb = (tile % ntiles) * 32, kb = (tile / ntiles) * 32;
    int tx = threadIdx.x, ty = threadIdx.y;   // 32 x 8
#pragma unroll
    for (int i = 0; i < 4; ++i)
        t32[ty + 8 * i][tx] = in[(size_t)(kb + ty + 8 * i) * N + nb + tx];
    __syncthreads();
#pragma unroll
    for (int i = 0; i < 4; ++i)
        out[(size_t)(nb + ty + 8 * i) * K + kb + tx] = f2bf(t32[tx][ty + 8 * i]);
}

// ---------------- bf16 MFMA GEMM: BK=64, XOR-swizzled LDS, XCD swizzle ------
// Main loop identical to the proven round-0 structure. New: (a) generalized
// bijective XCD swizzle for any Nt (identical to old formula at Nt=8);
// (b) coalesced epilogue: acc is transposed through LDS (32x136 f32, reusing
// the staging buffers) so 32 consecutive lanes cover 128 contiguous columns
// -> float4/short4 C stores and add-matrix loads (512B/256B per instruction).
// Same values, same add order -> bitwise-identical output.
template<int HAS_BIAS, int HAS_ADD, int ADD_BF, int HAS_SCALE, int OUT_F32, int OUT_BF, int SWZ>
__global__ __launch_bounds__(256, 4) void gemm_bf16(
    const short* __restrict__ A, const short* __restrict__ BT,
    const float* __restrict__ bias,
    const float* __restrict__ addf, const short* __restrict__ addb,
    const float* __restrict__ addscale,
    float* __restrict__ Cf, short* __restrict__ Cbf,
    int Mt, int Nt, int K) {
    __shared__ short LDSH[2 * 128 * 64];   // 32 KiB: As | Bs, reused by epilogue
    short* As = LDSH;
    short* Bs = LDSH + 128 * 64;
    int p = blockIdx.x;
    int mtile, ntile;
    if (SWZ) {           // bijective for grid%8==0: each XCD runs all ntiles
        int xcd = p & 7, q = p >> 3;      // of one mtile consecutively
        ntile = q % Nt;
        mtile = xcd + 8 * (q / Nt);
    } else {
        mtile = p % Mt;
        ntile = p / Mt;
    }
    int m0 = mtile * 128, n0 = ntile * 128;
    int N = Nt * 128;
    int tid = threadIdx.x;
    int lane = tid & 63;
    int w = tid >> 6;
    int quad = lane >> 4, r16 = lane & 15;
    int wm = (w & 1) * 64, wn = (w >> 1) * 64;

    f32x4 acc[4][4] = {};

    for (int k0 = 0; k0 < K; k0 += 64) {
#pragma unroll
        for (int it = 0; it < 4; ++it) {
            int seg = it * 256 + tid;          // 0..1023
            int row = seg >> 3, slot = seg & 7;
            int kc8 = slot ^ (row & 7);
            const short* gp = A + (size_t)(m0 + row) * K + k0 + kc8 * 8;
            __builtin_amdgcn_global_load_lds(
                (const __attribute__((address_space(1))) unsigned*)gp,
                (__attribute__((address_space(3))) unsigned*)(As + seg * 8), 16, 0, 0);
        }
#pragma unroll
        for (int it = 0; it < 4; ++it) {
            int seg = it * 256 + tid;
            int row = seg >> 3, slot = seg & 7;
            int kc8 = slot ^ (row & 7);
            const short* gp = BT + (size_t)(n0 + row) * K + k0 + kc8 * 8;
            __builtin_amdgcn_global_load_lds(
                (const __attribute__((address_space(1))) unsigned*)gp,
                (__attribute__((address_space(3))) unsigned*)(Bs + seg * 8), 16, 0, 0);
        }
        __syncthreads();

        const short* abase = As + (wm + r16) * 64;
        const short* bbase = Bs + (wn + r16) * 64;
        int sw = r16 & 7;
#pragma unroll
        for (int kk = 0; kk < 2; ++kk) {
            int phys = ((quad + 4 * kk) ^ sw) * 8;
            bf16x8 af[4], bfr[4];
#pragma unroll
            for (int i = 0; i < 4; ++i) af[i] = *(const bf16x8*)(abase + i * 16 * 64 + phys);
#pragma unroll
            for (int j = 0; j < 4; ++j) bfr[j] = *(const bf16x8*)(bbase + j * 16 * 64 + phys);
#pragma unroll
            for (int i = 0; i < 4; ++i)
#pragma unroll
                for (int j = 0; j < 4; ++j)
                    acc[i][j] = __builtin_amdgcn_mfma_f32_16x16x32_bf16(af[i], bfr[j], acc[i][j], 0, 0, 0);
        }
        __syncthreads();
    }

    // ---- coalesced epilogue: 4 i-slices of 32 rows x 128 cols through LDS ----
    float* ep = (float*)LDSH;                 // 32 x 136 f32 = 17408 B
    int cw = (tid & 31) * 4;                  // this thread's 4-col chunk
    int lrw = (w & 1) * 16;                   // local-row base (writer side)
    int pcb = (w >> 1) * 64;                  // col base (writer side)
    float4 b4 = {0.f, 0.f, 0.f, 0.f};
    float4 sc4 = {1.f, 1.f, 1.f, 1.f};
    if (HAS_BIAS) b4 = *(const float4*)(bias + n0 + cw);
    if (HAS_SCALE) sc4 = *(const float4*)(addscale + n0 + cw);
#pragma unroll
    for (int ih = 0; ih < 4; ++ih) {
        __syncthreads();
#pragma unroll
        for (int j = 0; j < 4; ++j)
#pragma unroll
            for (int pr = 0; pr < 4; ++pr)
                ep[(lrw + quad * 4 + pr) * 136 + pcb + j * 16 + r16] = acc[ih][j][pr];
        __syncthreads();
#pragma unroll
        for (int rb = 0; rb < 4; ++rb) {
            int lr = rb * 8 + (tid >> 5);
            int grow = m0 + ((lr >> 4) << 6) + ih * 16 + (lr & 15);
            size_t goff = (size_t)grow * N + n0 + cw;
            float4 v = *(const float4*)(ep + lr * 136 + cw);
            if (HAS_BIAS) { v.x += b4.x; v.y += b4.y; v.z += b4.z; v.w += b4.w; }
            if (HAS_ADD) {
                float ax, ay, az, aw;
                if (ADD_BF) {
                    short4 ab = *(const short4*)(addb + goff);
                    ax = bf2f(ab.x); ay = bf2f(ab.y); az = bf2f(ab.z); aw = bf2f(ab.w);
                } else {
                    float4 af4 = *(const float4*)(addf + goff);
                    ax = af4.x; ay = af4.y; az = af4.z; aw = af4.w;
                }
                v.x += sc4.x * ax; v.y += sc4.y * ay;
                v.z += sc4.z * az; v.w += sc4.w * aw;
            }
            if (OUT_F32) *(float4*)(Cf + goff) = v;
            if (OUT_BF) {
                short4 o;
                o.x = f2bf(v.x); o.y = f2bf(v.y); o.z = f2bf(v.z); o.w = f2bf(v.w);
                *(short4*)(Cbf + goff) = o;
            }
        }
    }
}

// ---------------- Chunked linear scan (round-5 proven form) -----------------
__global__ __launch_bounds__(128) void scan_p1(const float* __restrict__ s3,
                                               const float* __restrict__ A_log,
                                               float* __restrict__ hbuf,
                                               float* __restrict__ Ebuf) {
    int s = threadIdx.x;
    int c = blockIdx.x, b = blockIdx.y;
    float a = expf(-expf(A_log[s]));
    float h = 0.f;
    size_t base = (size_t)b * SEQ_LEN + (size_t)c * LCHUNK;
#pragma unroll 8
    for (int i = 0; i < LCHUNK; ++i) {
        size_t r = base + i;
        float u = s3[r * 384 + s] * s3[r * 384 + 128 + s];
        h = a * h + u;
        hbuf[r * 128 + s] = h;
    }
    Ebuf[((size_t)b * NCHUNK + c) * 128 + s] = h;
}

__global__ __launch_bounds__(512) void scan_p2(const float* __restrict__ A_log,
                                               const float* __restrict__ Ebuf,
                                               float* __restrict__ Gbuf) {
    int tid = threadIdx.x;
    int b = tid >> 7, s = tid & 127;
    float pw = expf(-expf(A_log[s]) * (float)LCHUNK);
    float G = 0.f;
    for (int c0 = 0; c0 < NCHUNK; c0 += 16) {
        float e[16];
#pragma unroll
        for (int t = 0; t < 16; ++t)
            e[t] = Ebuf[((size_t)b * NCHUNK + c0 + t) * 128 + s];
#pragma unroll
        for (int t = 0; t < 16; ++t) {
            G = pw * G + e[t];
            Gbuf[((size_t)b * NCHUNK + c0 + t) * 128 + s] = G;
        }
    }
}

__global__ __launch_bounds__(128) void scan_p3(const float* __restrict__ s3,
                                               const float* __restrict__ A_log,
                                               const float* __restrict__ hbuf,
                                               const float* __restrict__ Gbuf,
                                               short* __restrict__ ys_bf) {
    int s = threadIdx.x;
    int c = blockIdx.x, b = blockIdx.y;
    float a = expf(-expf(A_log[s]));
    float carry = (c == 0) ? 0.f : Gbuf[((size_t)b * NCHUNK + c - 1) * 128 + s];
    float p = a;
    size_t base = (size_t)b * SEQ_LEN + (size_t)c * LCHUNK;
#pragma unroll 8
    for (int i = 0; i < LCHUNK; ++i) {
        size_t r = base + i;
        float h = hbuf[r * 128 + s] + p * carry;
        p *= a;
        ys_bf[r * 128 + s] = f2bf(h * s3[r * 384 + 256 + s]);
    }
}

extern "C" void kernel_launch(void* const* d_in, const int* in_sizes, int n_in,
                              void* d_out, int out_size, void* d_ws, size_t ws_size,
                              hipStream_t stream) {
    const float* x     = (const float*)d_in[0];
    const float* ln_g  = (const float*)d_in[1];
    const float* ln_b  = (const float*)d_in[2];
    const float* W_in  = (const float*)d_in[3];
    const float* b_in  = (const float*)d_in[4];
    const float* W_xs  = (const float*)d_in[5];
    const float* W_B   = (const float*)d_in[6];
    const float* b_B   = (const float*)d_in[7];
    const float* W_C   = (const float*)d_in[8];
    const float* b_C   = (const float*)d_in[9];
    const float* A_log = (const float*)d_in[10];
    const float* Dvec  = (const float*)d_in[11];
    const float* W_so  = (const float*)d_in[12];
    const float* W_out = (const float*)d_in[13];
    const float* b_out = (const float*)d_in[14];
    float* out = (float*)d_out;

    // ---- workspace carve (bytes) ----
    char* w = (char*)d_ws;
    size_t off = 0;
    short* xn_bf = (short*)(w + off);                       // region 0: 32 MiB
    float* hbuf  = (float*)(w + off);                       //   reuses region 0 after GEMM1
    short* ys_bf = (short*)(w + off + 8388608);             //   after hbuf (8 MiB)
    off += (size_t)NTOK * D_MODEL * 2;
    short* z_bf  = (short*)(w + off);                       // region 1: 32 MiB
    off += (size_t)NTOK * D_MODEL * 2;
    short* y1_bf = (short*)(w + off);                       // region 2: 32 MiB
    off += (size_t)NTOK * D_MODEL * 2;
    float* s3    = (float*)(w + off); off += (size_t)NTOK * 384 * 4;       // 24 MiB
    float* Ebuf  = (float*)(w + off); off += (size_t)BATCH * NCHUNK * 128 * 4;
    float* Gbuf  = (float*)(w + off); off += (size_t)BATCH * NCHUNK * 128 * 4;
    short* W_inT  = (short*)(w + off); off += (size_t)D_MODEL * D_MODEL * 2;
    short* W3T    = (short*)(w + off); off += (size_t)384 * D_MODEL * 2;
    short* W_soT  = (short*)(w + off); off += (size_t)D_MODEL * D_STATE * 2;
    short* W_outT = (short*)(w + off); off += (size_t)D_MODEL * D_MODEL * 2;
    float* bias3  = (float*)(w + off); off += 2048;

    // ---- weight prep + LayerNorm (single launch; independent blocks) ----
    prep_ln_kernel<<<2561 + NTOK, dim3(32, 8), 0, stream>>>(
        W_in, W_xs, W_B, W_C, W_so, W_out, b_B, b_C,
        W_inT, W3T, W_soT, W_outT, bias3,
        x, ln_g, ln_b, xn_bf);

    const int Mt = NTOK / 128;   // 128
    // ---- 2) z = xn @ W_in + b_in  (bf16) ----
    gemm_bf16<1, 0, 0, 0, 0, 1, 1><<<Mt * 8, 256, 0, stream>>>(
        xn_bf, W_inT, b_in, nullptr, nullptr, nullptr,
        nullptr, z_bf, Mt, 8, D_MODEL);

    // ---- 3) s3 = z @ [W_xs|W_B|W_C] + bias3  (f32) ----
    gemm_bf16<1, 0, 0, 0, 1, 0, 1><<<Mt * 3, 256, 0, stream>>>(
        z_bf, W3T, bias3, nullptr, nullptr, nullptr,
        s3, nullptr, Mt, 3, D_MODEL);

    // ---- 4) chunked scan (fp32 exact), fused *C_sel -> ys_bf ----
    scan_p1<<<dim3(NCHUNK, BATCH), 128, 0, stream>>>(s3, A_log, hbuf, Ebuf);
    scan_p2<<<1, 512, 0, stream>>>(A_log, Ebuf, Gbuf);
    scan_p3<<<dim3(NCHUNK, BATCH), 128, 0, stream>>>(s3, A_log, hbuf, Gbuf, ys_bf);

    // ---- 5) y1 = ys @ W_so + D*z  (bf16 out, bf16 addmat) ----
    gemm_bf16<0, 1, 1, 1, 0, 1, 1><<<Mt * 8, 256, 0, stream>>>(
        ys_bf, W_soT, nullptr, nullptr, z_bf, Dvec,
        nullptr, y1_bf, Mt, 8, D_STATE);

    // ---- 6) out = y1 @ W_out + b_out + x (f32 residual) ----
    gemm_bf16<1, 1, 0, 0, 1, 0, 1><<<Mt * 8, 256, 0, stream>>>(
        y1_bf, W_outT, b_out, x, nullptr, nullptr,
        out, nullptr, Mt, 8, D_MODEL);
}